// Round 2
// baseline (409.936 us; speedup 1.0000x reference)
//
#include <hip/hip_runtime.h>
#include <hip/hip_bf16.h>
#include <math.h>

#define NNODES 50000
#define NEDGES 500000
#define ETOT   (NEDGES + NNODES)
#define DIN    128
#define CH     256
#define SLOPE  0.2f

#define SCAN_TILE 1024
#define NSCAN ((NNODES + SCAN_TILE - 1) / SCAN_TILE)   // 49
#define SCAT_BLOCKS ((ETOT + 255) / 256)               // 2149
#define FLAGBIT 0x40000000

typedef __attribute__((ext_vector_type(8))) short short8;
typedef __attribute__((ext_vector_type(4))) float f32x4;

typedef __attribute__((address_space(1))) void gvoid;
typedef __attribute__((address_space(3))) void lvoid;

static __device__ __forceinline__ void gload_lds16(const void* g, void* l) {
  // width-16 global->LDS: lane i lands at ldsbase + i*16 (wave-uniform base)
  __builtin_amdgcn_global_load_lds((const gvoid*)g, (lvoid*)l, 16, 0, 0);
}

static __device__ __forceinline__ float wave_reduce_max(float v) {
#pragma unroll
  for (int off = 32; off > 0; off >>= 1) v = fmaxf(v, __shfl_xor(v, off));
  return v;
}
static __device__ __forceinline__ float wave_reduce_sum(float v) {
#pragma unroll
  for (int off = 32; off > 0; off >>= 1) v += __shfl_xor(v, off);
  return v;
}
static __device__ __forceinline__ int wave_reduce_sum_i(int v) {
#pragma unroll
  for (int off = 32; off > 0; off >>= 1) v += __shfl_xor(v, off);
  return v;
}

static __device__ __forceinline__ unsigned short f2bf(float f) {
  unsigned int u = __float_as_uint(f);
  unsigned int r = (u + 0x7fffu + ((u >> 16) & 1u)) >> 16;
  return (unsigned short)r;
}
static __device__ __forceinline__ float bf2f(unsigned short u) {
  return __uint_as_float(((unsigned int)u) << 16);
}

// ---------------- fused init + weight cast: one dispatch ----------------
#define W1N4 (CH * DIN / 4)   // 8192
#define W2N4 (CH * CH / 4)    // 16384
__global__ __launch_bounds__(256) void init_and_cast(
    int* __restrict__ deg,
    float* __restrict__ eS1, float* __restrict__ eD1,
    float* __restrict__ eS2, float* __restrict__ eD2,
    const float* __restrict__ W1, const float* __restrict__ W2,
    unsigned short* __restrict__ Wb1, unsigned short* __restrict__ Wb2,
    int* __restrict__ tstate, int* __restrict__ done) {
  int i = blockIdx.x * 256 + threadIdx.x;
  if (i < NNODES) {
    deg[i] = 0;
    eS1[i] = 0.f; eD1[i] = 0.f;
    eS2[i] = 0.f; eD2[i] = 0.f;
  }
  if (i <= NSCAN) {
    if (i < NSCAN) tstate[i] = 0;
    else           *done = 0;
  }
  if (i < W1N4 + W2N4) {
    const float* src;
    unsigned short* dst;
    int j;
    if (i < W1N4) { src = W1; dst = Wb1; j = i; }
    else          { src = W2; dst = Wb2; j = i - W1N4; }
    float4 v = *(const float4*)(src + (size_t)j * 4);
    ushort4 o;
    o.x = f2bf(v.x); o.y = f2bf(v.y); o.z = f2bf(v.z); o.w = f2bf(v.w);
    *(ushort4*)(dst + (size_t)j * 4) = o;
  }
}

// ---------------- single-dispatch CSR build: lookback scan + fused scatter ----
// Blocks 0..NSCAN-1: per-tile scan, publish tile sum (device-scope release),
// poll lower-indexed tiles (decoupled lookback), write rowptr+cursor, bump done.
// Blocks NSCAN.. : spin on done==NSCAN (acquire), then scatter edges via cursor.
__global__ __launch_bounds__(256) void scan_scatter(
    const int* __restrict__ deg, int* __restrict__ rowptr, int* __restrict__ cursor,
    int* __restrict__ tstate, int* __restrict__ done,
    const int* __restrict__ ei, int* __restrict__ csr_src) {
  int tid = threadIdx.x;
  if (blockIdx.x >= NSCAN) {
    // ---- scatter tail ----
    if (tid == 0) {
      while (__hip_atomic_load(done, __ATOMIC_ACQUIRE, __HIP_MEMORY_SCOPE_AGENT) < NSCAN)
        __builtin_amdgcn_s_sleep(8);
    }
    __syncthreads();
    int e = (blockIdx.x - NSCAN) * 256 + tid;
    if (e < ETOT) {
      int src, dst;
      if (e < NEDGES) { src = ei[e]; dst = ei[NEDGES + e]; }
      else            { src = e - NEDGES; dst = src; }
      int slot = atomicAdd(&cursor[dst], 1);
      csr_src[slot] = src;
    }
    return;
  }
  // ---- scan tile ----
  __shared__ int wsums[4];
  __shared__ int s_boff;
  int b = blockIdx.x;
  int lane = tid & 63;
  int base = b * SCAN_TILE + tid * 4;
  int d[4];
  int s = 0;
#pragma unroll
  for (int j = 0; j < 4; j++) {
    d[j] = (base + j < NNODES) ? deg[base + j] : 0;
    s += d[j];
  }
  int x = s;
#pragma unroll
  for (int off = 1; off < 64; off <<= 1) {
    int t = __shfl_up(x, off);
    if (lane >= off) x += t;
  }
  if (lane == 63) wsums[tid >> 6] = x;
  __syncthreads();
  int total = wsums[0] + wsums[1] + wsums[2] + wsums[3];
  if (tid == 0)
    __hip_atomic_store(&tstate[b], total | FLAGBIT, __ATOMIC_RELEASE, __HIP_MEMORY_SCOPE_AGENT);
  if (tid < 64) {
    int acc = 0;
    if (lane < b) {
      int v;
      do {
        v = __hip_atomic_load(&tstate[lane], __ATOMIC_ACQUIRE, __HIP_MEMORY_SCOPE_AGENT);
        if (!(v & FLAGBIT)) __builtin_amdgcn_s_sleep(2);
      } while (!(v & FLAGBIT));
      acc = v & ~FLAGBIT;
    }
    acc = wave_reduce_sum_i(acc);
    if (lane == 0) s_boff = acc;
  }
  __syncthreads();
  int boff = s_boff;
  int woff = 0;
  int w = tid >> 6;
  for (int i = 0; i < w; i++) woff += wsums[i];
  int excl = boff + woff + (x - s);
#pragma unroll
  for (int j = 0; j < 4; j++) {
    if (base + j < NNODES) { rowptr[base + j] = excl; cursor[base + j] = excl; }
    excl += d[j];
  }
  if (b == NSCAN - 1 && tid == 0) rowptr[NNODES] = boff + total;
  __syncthreads();
  if (tid == 0)
    __hip_atomic_fetch_add(done, 1, __ATOMIC_RELEASE, __HIP_MEMORY_SCOPE_AGENT);
}

// ---------------- bf16 MFMA GEMM body + fused attention-score epilogue ----------------
// B tile (and A tile when input is bf16) staged via global_load_lds width-16
// into LINEAR [128][64]-short LDS with chunk-XOR swizzle applied on BOTH sides
// (rule #21): linear dest, inverse-swizzled per-lane global source, swizzled
// ds_read. Layer-1 A (fp32->bf16 conversion) keeps padded VGPR-staged path.
#define TM 128
#define TN 128
#define TK 64
#define LDA (TK + 8)          // padded layout, layer-1 A only
#define LDC (TN + 8)
#define SMEM_SHORTS (TM * LDC)  // 17408 shorts = 34816 B (covers all layouts)
#define GEMM_GRID (2 * ((NNODES + TM - 1) / TM))      // 782
#define DEG_BLOCKS ((ETOT + 255) / 256)               // 2149

template <bool XF>
static __device__ __forceinline__ void gemm_body(
    const float* __restrict__ Xf, const unsigned short* __restrict__ Xb,
    const unsigned short* __restrict__ W, int K,
    unsigned short* __restrict__ Hout, int M,
    const float* __restrict__ a_src, const float* __restrict__ a_dst,
    float* __restrict__ eS, float* __restrict__ eD,
    int bm, int bn) {
  __shared__ short smem[SMEM_SHORTS];
  short* As = smem;                                   // padded 9216 or linear 8192
  short* Bs = smem + (XF ? TM * LDA : TM * TK);       // linear 8192
  short* Cs = smem;
  int tid = threadIdx.x;
  int wid = tid >> 6;
  int lane = tid & 63;
  int wm = (wid & 1) * 64;
  int wn = (wid >> 1) * 64;
  int lrow = lane & 15;
  int lk8 = (lane >> 4) * 8;

  int srow = tid >> 3;          // layer-1 A staging row
  int skoff = (tid & 7) * 8;

  int rsub = lane >> 3;         // glds source mapping: lane -> (row R+rsub, chunk)
  int csub = lane & 7;
  int schunk = (csub ^ rsub) << 3;   // inverse-swizzled source chunk (shorts)

  f32x4 acc[4][4] = {};

  for (int k0 = 0; k0 < K; k0 += TK) {
    // ---- B tile: 4 glds instrs/wave, 8 rows each (linear dest + pre-swizzled src)
#pragma unroll
    for (int i = 0; i < 4; i++) {
      int R = i * 32 + wid * 8;
      const unsigned short* g = W + (size_t)(bn + R + rsub) * K + k0 + schunk;
      gload_lds16(g, &Bs[R * TK]);
    }
    if (XF) {
      // ---- A tile: fp32 load + convert + padded ds_write ----
#pragma unroll
      for (int i = 0; i < 4; i++) {
        int r = srow + 32 * i;
        int gm = bm + r;
        short8 v = {};
        if (gm < M) {
          const float* p = Xf + (size_t)gm * DIN + k0 + skoff;
          float4 f0 = *(const float4*)(p);
          float4 f1 = *(const float4*)(p + 4);
          v[0] = (short)f2bf(f0.x); v[1] = (short)f2bf(f0.y);
          v[2] = (short)f2bf(f0.z); v[3] = (short)f2bf(f0.w);
          v[4] = (short)f2bf(f1.x); v[5] = (short)f2bf(f1.y);
          v[6] = (short)f2bf(f1.z); v[7] = (short)f2bf(f1.w);
        }
        *(short8*)(&As[r * LDA + skoff]) = v;
      }
    } else {
      // ---- A tile: bf16 direct glds (rows >= M read in-workspace garbage; never used)
#pragma unroll
      for (int i = 0; i < 4; i++) {
        int R = i * 32 + wid * 8;
        const unsigned short* g = Xb + (size_t)(bm + R + rsub) * K + k0 + schunk;
        gload_lds16(g, &As[R * TK]);
      }
    }
    __syncthreads();
#pragma unroll
    for (int kk = 0; kk < TK; kk += 32) {
      short8 a[4], b[4];
#pragma unroll
      for (int mi = 0; mi < 4; mi++) {
        int ar = wm + mi * 16 + lrow;
        if (XF) {
          a[mi] = *(const short8*)(&As[ar * LDA + kk + lk8]);
        } else {
          int ac = (kk + lk8) >> 3;
          a[mi] = *(const short8*)(&As[ar * TK + ((ac ^ (ar & 7)) << 3)]);
        }
      }
#pragma unroll
      for (int ni = 0; ni < 4; ni++) {
        int br = wn + ni * 16 + lrow;
        int bc = (kk + lk8) >> 3;
        b[ni] = *(const short8*)(&Bs[br * TK + ((bc ^ (br & 7)) << 3)]);
      }
#pragma unroll
      for (int mi = 0; mi < 4; mi++)
#pragma unroll
        for (int ni = 0; ni < 4; ni++)
          acc[mi][ni] = __builtin_amdgcn_mfma_f32_16x16x32_bf16(a[mi], b[ni], acc[mi][ni], 0, 0, 0);
    }
    __syncthreads();
  }

  int crow = (lane >> 4) * 4;
  int ccol = lane & 15;

  // ---- fused score epilogue ----
  float asv[4], adv[4];
#pragma unroll
  for (int ni = 0; ni < 4; ni++) {
    int c = bn + wn + ni * 16 + ccol;
    asv[ni] = a_src[c];
    adv[ni] = a_dst[c];
  }
#pragma unroll
  for (int mi = 0; mi < 4; mi++) {
#pragma unroll
    for (int r = 0; r < 4; r++) {
      float s = 0.f, d = 0.f;
#pragma unroll
      for (int ni = 0; ni < 4; ni++) {
        float h = acc[mi][ni][r];
        s += h * asv[ni];
        d += h * adv[ni];
      }
#pragma unroll
      for (int off = 1; off < 16; off <<= 1) {
        s += __shfl_xor(s, off);
        d += __shfl_xor(d, off);
      }
      int gm = bm + wm + mi * 16 + crow + r;
      if (ccol == 0 && gm < M) {
        atomicAdd(&eS[gm], s);
        atomicAdd(&eD[gm], d);
      }
    }
  }

  // ---- C-store via padded LDS tile -> coalesced short8 global stores ----
#pragma unroll
  for (int mi = 0; mi < 4; mi++) {
#pragma unroll
    for (int ni = 0; ni < 4; ni++) {
#pragma unroll
      for (int r = 0; r < 4; r++) {
        int row = wm + mi * 16 + crow + r;
        int col = wn + ni * 16 + ccol;
        Cs[row * LDC + col] = (short)f2bf(acc[mi][ni][r]);
      }
    }
  }
  __syncthreads();
  int orow = tid >> 4;
  int ocol = (tid & 15) * 8;
#pragma unroll
  for (int pp = 0; pp < 8; pp++) {
    int row = pp * 16 + orow;
    int gm = bm + row;
    if (gm < M) {
      short8 v = *(const short8*)(&Cs[row * LDC + ocol]);
      *(short8*)(&Hout[(size_t)gm * CH + bn + ocol]) = v;
    }
  }
}

// layer-1 GEMM with degree-count blocks fused at the grid tail
__global__ __launch_bounds__(256) void gemm1_deg(
    const float* __restrict__ Xf, const unsigned short* __restrict__ W,
    unsigned short* __restrict__ Hout,
    const float* __restrict__ a_src, const float* __restrict__ a_dst,
    float* __restrict__ eS, float* __restrict__ eD,
    const int* __restrict__ ei, int* __restrict__ deg) {
  if (blockIdx.x >= GEMM_GRID) {
    int e = (blockIdx.x - GEMM_GRID) * 256 + threadIdx.x;
    if (e < ETOT) {
      int dst = (e < NEDGES) ? ei[NEDGES + e] : (e - NEDGES);
      atomicAdd(&deg[dst], 1);
    }
    return;
  }
  int bn = (blockIdx.x & 1) * TN;
  int bm = (blockIdx.x >> 1) * TM;
  gemm_body<true>(Xf, (const unsigned short*)nullptr, W, DIN, Hout, NNODES,
                  a_src, a_dst, eS, eD, bm, bn);
}

__global__ __launch_bounds__(256) void gemm_l2(
    const unsigned short* __restrict__ Xb, const unsigned short* __restrict__ W,
    unsigned short* __restrict__ Hout,
    const float* __restrict__ a_src, const float* __restrict__ a_dst,
    float* __restrict__ eS, float* __restrict__ eD) {
  int bn = blockIdx.x * TN;
  int bm = blockIdx.y * TM;
  gemm_body<false>((const float*)nullptr, Xb, W, CH, Hout, NNODES,
                   a_src, a_dst, eS, eD, bm, bn);
}

// ---------------- per-node softmax + aggregate (+bias, +ReLU) ----------------
__global__ __launch_bounds__(256) void aggregate_kernel(
    const unsigned short* __restrict__ Hmb, const float* __restrict__ eS,
    const float* __restrict__ eD, const int* __restrict__ rowptr,
    const int* __restrict__ csr_src, const float* __restrict__ bias,
    float* __restrict__ out, int outOffset, unsigned short* __restrict__ xout) {
  int n = blockIdx.x * 4 + (threadIdx.x >> 6);
  if (n >= NNODES) return;
  int lane = threadIdx.x & 63;
  int half = lane >> 5;        // which edge of the pair this lane serves
  int cg = lane & 31;          // channel group: channels cg*8 .. cg*8+7
  int beg = rowptr[n], end = rowptr[n + 1];
  int deg = end - beg;
  float ed = eD[n];

  float acc8[8];
#pragma unroll
  for (int k = 0; k < 8; k++) acc8[k] = 0.f;

  if (deg <= 64) {
    int src = 0;
    float e = -1e30f;
    if (lane < deg) {
      src = csr_src[beg + lane];              // coalesced
      float t = eS[src] + ed;                 // lane-parallel gather
      e = (t >= 0.f) ? t : SLOPE * t;
    }
    float m = wave_reduce_max(e);
    float p = (lane < deg) ? __expf(e - m) : 0.f;
    float inv = 1.f / (wave_reduce_sum(p) + 1e-16f);
    float av = p * inv;                       // this lane's alpha

    for (int j0 = 0; j0 < deg; j0 += 16) {
      uint4 hv[8];
      float al[8];
#pragma unroll
      for (int t = 0; t < 8; t++) {
        int j = j0 + 2 * t + half;
        int jj = (j < deg) ? j : deg - 1;     // tail dups last edge (L1-hot)
        int sj = __shfl(src, jj);
        float aj = __shfl(av, jj);
        al[t] = (j < deg) ? aj : 0.f;
        hv[t] = *(const uint4*)(Hmb + (size_t)sj * CH + cg * 8);
      }
#pragma unroll
      for (int t = 0; t < 8; t++) {
        acc8[0] += al[t] * __uint_as_float(hv[t].x << 16);
        acc8[1] += al[t] * __uint_as_float(hv[t].x & 0xffff0000u);
        acc8[2] += al[t] * __uint_as_float(hv[t].y << 16);
        acc8[3] += al[t] * __uint_as_float(hv[t].y & 0xffff0000u);
        acc8[4] += al[t] * __uint_as_float(hv[t].z << 16);
        acc8[5] += al[t] * __uint_as_float(hv[t].z & 0xffff0000u);
        acc8[6] += al[t] * __uint_as_float(hv[t].w << 16);
        acc8[7] += al[t] * __uint_as_float(hv[t].w & 0xffff0000u);
      }
    }
  } else {
    float m = -1e30f;
    for (int i = lane; i < deg; i += 64) {
      float e = eS[csr_src[beg + i]] + ed;
      e = (e >= 0.f) ? e : SLOPE * e;
      m = fmaxf(m, e);
    }
    m = wave_reduce_max(m);
    float ds = 0.f;
    for (int i = lane; i < deg; i += 64) {
      float e = eS[csr_src[beg + i]] + ed;
      e = (e >= 0.f) ? e : SLOPE * e;
      ds += __expf(e - m);
    }
    float inv = 1.f / (wave_reduce_sum(ds) + 1e-16f);
    for (int j = 0; j < deg; j += 2) {
      int jj = j + half;
      int k = beg + ((jj < deg) ? jj : deg - 1);
      int s = csr_src[k];
      float e = eS[s] + ed;
      e = (e >= 0.f) ? e : SLOPE * e;
      float alpha = (jj < deg) ? __expf(e - m) * inv : 0.f;
      uint4 u = *(const uint4*)(Hmb + (size_t)s * CH + cg * 8);
      acc8[0] += alpha * __uint_as_float(u.x << 16);
      acc8[1] += alpha * __uint_as_float(u.x & 0xffff0000u);
      acc8[2] += alpha * __uint_as_float(u.y << 16);
      acc8[3] += alpha * __uint_as_float(u.y & 0xffff0000u);
      acc8[4] += alpha * __uint_as_float(u.z << 16);
      acc8[5] += alpha * __uint_as_float(u.z & 0xffff0000u);
      acc8[6] += alpha * __uint_as_float(u.w << 16);
      acc8[7] += alpha * __uint_as_float(u.w & 0xffff0000u);
    }
  }

  // combine the two half-wave partial sums (even-j half + odd-j half)
#pragma unroll
  for (int k = 0; k < 8; k++) acc8[k] += __shfl_xor(acc8[k], 32);

  // lane writes 4 channels: cbase = cg*8 + half*4 (static-index selects only)
  float a0 = half ? acc8[4] : acc8[0];
  float a1 = half ? acc8[5] : acc8[1];
  float a2 = half ? acc8[6] : acc8[2];
  float a3 = half ? acc8[7] : acc8[3];
  int cbase = cg * 8 + half * 4;
  float4 b = *(const float4*)(bias + cbase);
  float4 o;
  o.x = fmaxf(a0 + b.x, 0.f);
  o.y = fmaxf(a1 + b.y, 0.f);
  o.z = fmaxf(a2 + b.z, 0.f);
  o.w = fmaxf(a3 + b.w, 0.f);
  *(float4*)(out + (size_t)n * 512 + outOffset + cbase) = o;
  if (xout) {
    ushort4 ob;
    ob.x = f2bf(o.x); ob.y = f2bf(o.y); ob.z = f2bf(o.z); ob.w = f2bf(o.w);
    *(ushort4*)(xout + (size_t)n * CH + cbase) = ob;
  }
}

extern "C" void kernel_launch(void* const* d_in, const int* in_sizes, int n_in,
                              void* d_out, int out_size, void* d_ws, size_t ws_size,
                              hipStream_t stream) {
  const float* x   = (const float*)d_in[0];
  const int*   ei  = (const int*)d_in[1];
  const float* W1  = (const float*)d_in[2];
  const float* a1s = (const float*)d_in[3];
  const float* a1d = (const float*)d_in[4];
  const float* b1  = (const float*)d_in[5];
  const float* W2  = (const float*)d_in[6];
  const float* a2s = (const float*)d_in[7];
  const float* a2d = (const float*)d_in[8];
  const float* b2  = (const float*)d_in[9];
  float* out = (float*)d_out;

  char* ws = (char*)d_ws;
  size_t off = 0;
  auto alloc = [&](size_t bytes) -> void* {
    void* p = ws + off;
    off = (off + bytes + 255) & ~(size_t)255;
    return p;
  };
  unsigned short* Hmb    = (unsigned short*)alloc(sizeof(short) * (size_t)NNODES * CH);
  unsigned short* Xb     = (unsigned short*)alloc(sizeof(short) * (size_t)NNODES * CH);
  unsigned short* Wb1    = (unsigned short*)alloc(sizeof(short) * CH * DIN);
  unsigned short* Wb2    = (unsigned short*)alloc(sizeof(short) * CH * CH);
  float*          eS1    = (float*)alloc(sizeof(float) * NNODES);
  float*          eD1    = (float*)alloc(sizeof(float) * NNODES);
  float*          eS2    = (float*)alloc(sizeof(float) * NNODES);
  float*          eD2    = (float*)alloc(sizeof(float) * NNODES);
  int*            rowptr = (int*)alloc(sizeof(int) * (NNODES + 1));
  int*            cursor = (int*)alloc(sizeof(int) * NNODES);
  int*            csrsrc = (int*)alloc(sizeof(int) * ETOT);
  int*            deg    = (int*)alloc(sizeof(int) * NNODES);
  int*            tstate = (int*)alloc(sizeof(int) * NSCAN);
  int*            done   = (int*)alloc(sizeof(int));

  int nblk4 = (NNODES + 3) / 4;

  // 1) init + weight casts + lookback-state zero (1 dispatch)
  init_and_cast<<<(NNODES + 255) / 256, 256, 0, stream>>>(deg, eS1, eD1, eS2, eD2,
                                                          W1, W2, Wb1, Wb2, tstate, done);

  // 2) layer-1 GEMM with degree counting fused at the grid tail (overlapped)
  gemm1_deg<<<GEMM_GRID + DEG_BLOCKS, 256, 0, stream>>>(x, Wb1, Hmb, a1s, a1d,
                                                        eS1, eD1, ei, deg);

  // 3) CSR build: lookback scan + fused scatter (1 dispatch replaces 4)
  scan_scatter<<<NSCAN + SCAT_BLOCKS, 256, 0, stream>>>(deg, rowptr, cursor,
                                                        tstate, done, ei, csrsrc);

  // 4) layer 1 aggregate
  aggregate_kernel<<<nblk4, 256, 0, stream>>>(Hmb, eS1, eD1, rowptr, csrsrc, b1, out, 0, Xb);

  // 5) layer 2 GEMM
  gemm_l2<<<dim3(2, (NNODES + TM - 1) / TM), 256, 0, stream>>>(Xb, Wb2, Hmb, a2s, a2d, eS2, eD2);

  // 6) layer 2 aggregate
  aggregate_kernel<<<nblk4, 256, 0, stream>>>(Hmb, eS2, eD2, rowptr, csrsrc, b2, out, 256,
                                              (unsigned short*)nullptr);
}

// Round 3
// 318.622 us; speedup vs baseline: 1.2866x; 1.2866x over previous
//
#include <hip/hip_runtime.h>
#include <hip/hip_bf16.h>
#include <math.h>

#define NNODES 50000
#define NEDGES 500000
#define ETOT   (NEDGES + NNODES)
#define DIN    128
#define CH     256
#define SLOPE  0.2f

#define SCAN_TILE 1024
#define NSCAN ((NNODES + SCAN_TILE - 1) / SCAN_TILE)   // 49
#define FLAGBIT 0x40000000

typedef __attribute__((ext_vector_type(8))) short short8;
typedef __attribute__((ext_vector_type(4))) float f32x4;

typedef __attribute__((address_space(1))) void gvoid;
typedef __attribute__((address_space(3))) void lvoid;

static __device__ __forceinline__ void gload_lds16(const void* g, void* l) {
  // width-16 global->LDS: lane i lands at ldsbase + i*16 (wave-uniform base)
  __builtin_amdgcn_global_load_lds((const gvoid*)g, (lvoid*)l, 16, 0, 0);
}

static __device__ __forceinline__ float wave_reduce_max(float v) {
#pragma unroll
  for (int off = 32; off > 0; off >>= 1) v = fmaxf(v, __shfl_xor(v, off));
  return v;
}
static __device__ __forceinline__ float wave_reduce_sum(float v) {
#pragma unroll
  for (int off = 32; off > 0; off >>= 1) v += __shfl_xor(v, off);
  return v;
}
static __device__ __forceinline__ int wave_reduce_sum_i(int v) {
#pragma unroll
  for (int off = 32; off > 0; off >>= 1) v += __shfl_xor(v, off);
  return v;
}

static __device__ __forceinline__ unsigned short f2bf(float f) {
  unsigned int u = __float_as_uint(f);
  unsigned int r = (u + 0x7fffu + ((u >> 16) & 1u)) >> 16;
  return (unsigned short)r;
}
static __device__ __forceinline__ float bf2f(unsigned short u) {
  return __uint_as_float(((unsigned int)u) << 16);
}

// ---------------- fused init + weight cast: one dispatch ----------------
#define W1N4 (CH * DIN / 4)   // 8192
#define W2N4 (CH * CH / 4)    // 16384
__global__ __launch_bounds__(256) void init_and_cast(
    int* __restrict__ deg,
    float* __restrict__ eS1, float* __restrict__ eD1,
    float* __restrict__ eS2, float* __restrict__ eD2,
    const float* __restrict__ W1, const float* __restrict__ W2,
    unsigned short* __restrict__ Wb1, unsigned short* __restrict__ Wb2,
    int* __restrict__ tstate) {
  int i = blockIdx.x * 256 + threadIdx.x;
  if (i < NNODES) {
    deg[i] = 0;
    eS1[i] = 0.f; eD1[i] = 0.f;
    eS2[i] = 0.f; eD2[i] = 0.f;
  }
  if (i < NSCAN) tstate[i] = 0;
  if (i < W1N4 + W2N4) {
    const float* src;
    unsigned short* dst;
    int j;
    if (i < W1N4) { src = W1; dst = Wb1; j = i; }
    else          { src = W2; dst = Wb2; j = i - W1N4; }
    float4 v = *(const float4*)(src + (size_t)j * 4);
    ushort4 o;
    o.x = f2bf(v.x); o.y = f2bf(v.y); o.z = f2bf(v.z); o.w = f2bf(v.w);
    *(ushort4*)(dst + (size_t)j * 4) = o;
  }
}

// ---------------- decoupled-lookback scan: ONE dispatch, 49 blocks only ----------------
// Each tile publishes its sum (release), polls lower tiles (acquire), writes
// rowptr + cursor. 49 blocks on 4 cachelines: negligible contention (unlike the
// round-2 fused-scatter spin with 2149 pollers, which serialized the fabric).
__global__ __launch_bounds__(256) void scan_lookback(
    const int* __restrict__ deg, int* __restrict__ rowptr, int* __restrict__ cursor,
    int* __restrict__ tstate) {
  __shared__ int wsums[4];
  __shared__ int s_boff;
  int b = blockIdx.x;
  int tid = threadIdx.x;
  int lane = tid & 63;
  int base = b * SCAN_TILE + tid * 4;
  int d[4];
  int s = 0;
#pragma unroll
  for (int j = 0; j < 4; j++) {
    d[j] = (base + j < NNODES) ? deg[base + j] : 0;
    s += d[j];
  }
  int x = s;
#pragma unroll
  for (int off = 1; off < 64; off <<= 1) {
    int t = __shfl_up(x, off);
    if (lane >= off) x += t;
  }
  if (lane == 63) wsums[tid >> 6] = x;
  __syncthreads();
  int total = wsums[0] + wsums[1] + wsums[2] + wsums[3];
  if (tid == 0)
    __hip_atomic_store(&tstate[b], total | FLAGBIT, __ATOMIC_RELEASE, __HIP_MEMORY_SCOPE_AGENT);
  if (tid < 64) {
    int acc = 0;
    if (lane < b) {
      int v;
      do {
        v = __hip_atomic_load(&tstate[lane], __ATOMIC_ACQUIRE, __HIP_MEMORY_SCOPE_AGENT);
        if (!(v & FLAGBIT)) __builtin_amdgcn_s_sleep(2);
      } while (!(v & FLAGBIT));
      acc = v & ~FLAGBIT;
    }
    acc = wave_reduce_sum_i(acc);
    if (lane == 0) s_boff = acc;
  }
  __syncthreads();
  int boff = s_boff;
  int woff = 0;
  int w = tid >> 6;
  for (int i = 0; i < w; i++) woff += wsums[i];
  int excl = boff + woff + (x - s);
#pragma unroll
  for (int j = 0; j < 4; j++) {
    if (base + j < NNODES) { rowptr[base + j] = excl; cursor[base + j] = excl; }
    excl += d[j];
  }
  if (b == NSCAN - 1 && tid == 0) rowptr[NNODES] = boff + total;
}

__global__ void scatter_kernel(const int* __restrict__ ei, int* __restrict__ cursor,
                               int* __restrict__ csr_src) {
  int e = blockIdx.x * blockDim.x + threadIdx.x;
  if (e >= ETOT) return;
  int src, dst;
  if (e < NEDGES) { src = ei[e]; dst = ei[NEDGES + e]; }
  else            { src = e - NEDGES; dst = src; }
  int slot = atomicAdd(&cursor[dst], 1);
  csr_src[slot] = src;
}

// ---------------- bf16 MFMA GEMM body + fused attention-score epilogue ----------------
// B tile (and A tile when input is bf16) staged via global_load_lds width-16
// into LINEAR [128][64]-short LDS with chunk-XOR swizzle applied on BOTH sides
// (rule #21): linear dest, inverse-swizzled per-lane global source, swizzled
// ds_read. Layer-1 A (fp32->bf16 conversion) keeps padded VGPR-staged path.
#define TM 128
#define TN 128
#define TK 64
#define LDA (TK + 8)          // padded layout, layer-1 A only
#define LDC (TN + 8)
#define SMEM_SHORTS (TM * LDC)  // 17408 shorts = 34816 B (covers all layouts)
#define GEMM_GRID (2 * ((NNODES + TM - 1) / TM))      // 782
#define DEG_BLOCKS ((ETOT + 255) / 256)               // 2149

template <bool XF>
static __device__ __forceinline__ void gemm_body(
    const float* __restrict__ Xf, const unsigned short* __restrict__ Xb,
    const unsigned short* __restrict__ W, int K,
    unsigned short* __restrict__ Hout, int M,
    const float* __restrict__ a_src, const float* __restrict__ a_dst,
    float* __restrict__ eS, float* __restrict__ eD,
    int bm, int bn) {
  __shared__ short smem[SMEM_SHORTS];
  short* As = smem;                                   // padded 9216 or linear 8192
  short* Bs = smem + (XF ? TM * LDA : TM * TK);       // linear 8192
  short* Cs = smem;
  int tid = threadIdx.x;
  int wid = tid >> 6;
  int lane = tid & 63;
  int wm = (wid & 1) * 64;
  int wn = (wid >> 1) * 64;
  int lrow = lane & 15;
  int lk8 = (lane >> 4) * 8;

  int srow = tid >> 3;          // layer-1 A staging row
  int skoff = (tid & 7) * 8;

  int rsub = lane >> 3;         // glds source mapping: lane -> (row R+rsub, chunk)
  int csub = lane & 7;
  int schunk = (csub ^ rsub) << 3;   // inverse-swizzled source chunk (shorts)

  f32x4 acc[4][4] = {};

  for (int k0 = 0; k0 < K; k0 += TK) {
    // ---- B tile: 4 glds instrs/wave, 8 rows each (linear dest + pre-swizzled src)
#pragma unroll
    for (int i = 0; i < 4; i++) {
      int R = i * 32 + wid * 8;
      const unsigned short* g = W + (size_t)(bn + R + rsub) * K + k0 + schunk;
      gload_lds16(g, &Bs[R * TK]);
    }
    if (XF) {
      // ---- A tile: fp32 load + convert + padded ds_write ----
#pragma unroll
      for (int i = 0; i < 4; i++) {
        int r = srow + 32 * i;
        int gm = bm + r;
        short8 v = {};
        if (gm < M) {
          const float* p = Xf + (size_t)gm * DIN + k0 + skoff;
          float4 f0 = *(const float4*)(p);
          float4 f1 = *(const float4*)(p + 4);
          v[0] = (short)f2bf(f0.x); v[1] = (short)f2bf(f0.y);
          v[2] = (short)f2bf(f0.z); v[3] = (short)f2bf(f0.w);
          v[4] = (short)f2bf(f1.x); v[5] = (short)f2bf(f1.y);
          v[6] = (short)f2bf(f1.z); v[7] = (short)f2bf(f1.w);
        }
        *(short8*)(&As[r * LDA + skoff]) = v;
      }
    } else {
      // ---- A tile: bf16 direct glds (rows >= M read in-workspace garbage; masked downstream)
#pragma unroll
      for (int i = 0; i < 4; i++) {
        int R = i * 32 + wid * 8;
        const unsigned short* g = Xb + (size_t)(bm + R + rsub) * K + k0 + schunk;
        gload_lds16(g, &As[R * TK]);
      }
    }
    __syncthreads();
#pragma unroll
    for (int kk = 0; kk < TK; kk += 32) {
      short8 a[4], b[4];
#pragma unroll
      for (int mi = 0; mi < 4; mi++) {
        int ar = wm + mi * 16 + lrow;
        if (XF) {
          a[mi] = *(const short8*)(&As[ar * LDA + kk + lk8]);
        } else {
          int ac = (kk + lk8) >> 3;
          a[mi] = *(const short8*)(&As[ar * TK + ((ac ^ (ar & 7)) << 3)]);
        }
      }
#pragma unroll
      for (int ni = 0; ni < 4; ni++) {
        int br = wn + ni * 16 + lrow;
        int bc = (kk + lk8) >> 3;
        b[ni] = *(const short8*)(&Bs[br * TK + ((bc ^ (br & 7)) << 3)]);
      }
#pragma unroll
      for (int mi = 0; mi < 4; mi++)
#pragma unroll
        for (int ni = 0; ni < 4; ni++)
          acc[mi][ni] = __builtin_amdgcn_mfma_f32_16x16x32_bf16(a[mi], b[ni], acc[mi][ni], 0, 0, 0);
    }
    __syncthreads();
  }

  int crow = (lane >> 4) * 4;
  int ccol = lane & 15;

  // ---- fused score epilogue ----
  float asv[4], adv[4];
#pragma unroll
  for (int ni = 0; ni < 4; ni++) {
    int c = bn + wn + ni * 16 + ccol;
    asv[ni] = a_src[c];
    adv[ni] = a_dst[c];
  }
#pragma unroll
  for (int mi = 0; mi < 4; mi++) {
#pragma unroll
    for (int r = 0; r < 4; r++) {
      float s = 0.f, d = 0.f;
#pragma unroll
      for (int ni = 0; ni < 4; ni++) {
        float h = acc[mi][ni][r];
        s += h * asv[ni];
        d += h * adv[ni];
      }
#pragma unroll
      for (int off = 1; off < 16; off <<= 1) {
        s += __shfl_xor(s, off);
        d += __shfl_xor(d, off);
      }
      int gm = bm + wm + mi * 16 + crow + r;
      if (ccol == 0 && gm < M) {
        atomicAdd(&eS[gm], s);
        atomicAdd(&eD[gm], d);
      }
    }
  }

  // ---- C-store via padded LDS tile -> coalesced short8 global stores ----
#pragma unroll
  for (int mi = 0; mi < 4; mi++) {
#pragma unroll
    for (int ni = 0; ni < 4; ni++) {
#pragma unroll
      for (int r = 0; r < 4; r++) {
        int row = wm + mi * 16 + crow + r;
        int col = wn + ni * 16 + ccol;
        Cs[row * LDC + col] = (short)f2bf(acc[mi][ni][r]);
      }
    }
  }
  __syncthreads();
  int orow = tid >> 4;
  int ocol = (tid & 15) * 8;
#pragma unroll
  for (int pp = 0; pp < 8; pp++) {
    int row = pp * 16 + orow;
    int gm = bm + row;
    if (gm < M) {
      short8 v = *(const short8*)(&Cs[row * LDC + ocol]);
      *(short8*)(&Hout[(size_t)gm * CH + bn + ocol]) = v;
    }
  }
}

// layer-1 GEMM with degree-count blocks fused at the grid tail
__global__ __launch_bounds__(256) void gemm1_deg(
    const float* __restrict__ Xf, const unsigned short* __restrict__ W,
    unsigned short* __restrict__ Hout,
    const float* __restrict__ a_src, const float* __restrict__ a_dst,
    float* __restrict__ eS, float* __restrict__ eD,
    const int* __restrict__ ei, int* __restrict__ deg) {
  if (blockIdx.x >= GEMM_GRID) {
    int e = (blockIdx.x - GEMM_GRID) * 256 + threadIdx.x;
    if (e < ETOT) {
      int dst = (e < NEDGES) ? ei[NEDGES + e] : (e - NEDGES);
      atomicAdd(&deg[dst], 1);
    }
    return;
  }
  int bn = (blockIdx.x & 1) * TN;
  int bm = (blockIdx.x >> 1) * TM;
  gemm_body<true>(Xf, (const unsigned short*)nullptr, W, DIN, Hout, NNODES,
                  a_src, a_dst, eS, eD, bm, bn);
}

__global__ __launch_bounds__(256) void gemm_l2(
    const unsigned short* __restrict__ Xb, const unsigned short* __restrict__ W,
    unsigned short* __restrict__ Hout,
    const float* __restrict__ a_src, const float* __restrict__ a_dst,
    float* __restrict__ eS, float* __restrict__ eD) {
  int bn = blockIdx.x * TN;
  int bm = blockIdx.y * TM;
  gemm_body<false>((const float*)nullptr, Xb, W, CH, Hout, NNODES,
                   a_src, a_dst, eS, eD, bm, bn);
}

// ---------------- per-node softmax + aggregate (+bias, +ReLU) ----------------
__global__ __launch_bounds__(256) void aggregate_kernel(
    const unsigned short* __restrict__ Hmb, const float* __restrict__ eS,
    const float* __restrict__ eD, const int* __restrict__ rowptr,
    const int* __restrict__ csr_src, const float* __restrict__ bias,
    float* __restrict__ out, int outOffset, unsigned short* __restrict__ xout) {
  int n = blockIdx.x * 4 + (threadIdx.x >> 6);
  if (n >= NNODES) return;
  int lane = threadIdx.x & 63;
  int half = lane >> 5;        // which edge of the pair this lane serves
  int cg = lane & 31;          // channel group: channels cg*8 .. cg*8+7
  int beg = rowptr[n], end = rowptr[n + 1];
  int deg = end - beg;
  float ed = eD[n];

  float acc8[8];
#pragma unroll
  for (int k = 0; k < 8; k++) acc8[k] = 0.f;

  if (deg <= 64) {
    int src = 0;
    float e = -1e30f;
    if (lane < deg) {
      src = csr_src[beg + lane];              // coalesced
      float t = eS[src] + ed;                 // lane-parallel gather
      e = (t >= 0.f) ? t : SLOPE * t;
    }
    float m = wave_reduce_max(e);
    float p = (lane < deg) ? __expf(e - m) : 0.f;
    float inv = 1.f / (wave_reduce_sum(p) + 1e-16f);
    float av = p * inv;                       // this lane's alpha

    for (int j0 = 0; j0 < deg; j0 += 16) {
      uint4 hv[8];
      float al[8];
#pragma unroll
      for (int t = 0; t < 8; t++) {
        int j = j0 + 2 * t + half;
        int jj = (j < deg) ? j : deg - 1;     // tail dups last edge (L1-hot)
        int sj = __shfl(src, jj);
        float aj = __shfl(av, jj);
        al[t] = (j < deg) ? aj : 0.f;
        hv[t] = *(const uint4*)(Hmb + (size_t)sj * CH + cg * 8);
      }
#pragma unroll
      for (int t = 0; t < 8; t++) {
        acc8[0] += al[t] * __uint_as_float(hv[t].x << 16);
        acc8[1] += al[t] * __uint_as_float(hv[t].x & 0xffff0000u);
        acc8[2] += al[t] * __uint_as_float(hv[t].y << 16);
        acc8[3] += al[t] * __uint_as_float(hv[t].y & 0xffff0000u);
        acc8[4] += al[t] * __uint_as_float(hv[t].z << 16);
        acc8[5] += al[t] * __uint_as_float(hv[t].z & 0xffff0000u);
        acc8[6] += al[t] * __uint_as_float(hv[t].w << 16);
        acc8[7] += al[t] * __uint_as_float(hv[t].w & 0xffff0000u);
      }
    }
  } else {
    float m = -1e30f;
    for (int i = lane; i < deg; i += 64) {
      float e = eS[csr_src[beg + i]] + ed;
      e = (e >= 0.f) ? e : SLOPE * e;
      m = fmaxf(m, e);
    }
    m = wave_reduce_max(m);
    float ds = 0.f;
    for (int i = lane; i < deg; i += 64) {
      float e = eS[csr_src[beg + i]] + ed;
      e = (e >= 0.f) ? e : SLOPE * e;
      ds += __expf(e - m);
    }
    float inv = 1.f / (wave_reduce_sum(ds) + 1e-16f);
    for (int j = 0; j < deg; j += 2) {
      int jj = j + half;
      int k = beg + ((jj < deg) ? jj : deg - 1);
      int s = csr_src[k];
      float e = eS[s] + ed;
      e = (e >= 0.f) ? e : SLOPE * e;
      float alpha = (jj < deg) ? __expf(e - m) * inv : 0.f;
      uint4 u = *(const uint4*)(Hmb + (size_t)s * CH + cg * 8);
      acc8[0] += alpha * __uint_as_float(u.x << 16);
      acc8[1] += alpha * __uint_as_float(u.x & 0xffff0000u);
      acc8[2] += alpha * __uint_as_float(u.y << 16);
      acc8[3] += alpha * __uint_as_float(u.y & 0xffff0000u);
      acc8[4] += alpha * __uint_as_float(u.z << 16);
      acc8[5] += alpha * __uint_as_float(u.z & 0xffff0000u);
      acc8[6] += alpha * __uint_as_float(u.w << 16);
      acc8[7] += alpha * __uint_as_float(u.w & 0xffff0000u);
    }
  }

  // combine the two half-wave partial sums (even-j half + odd-j half)
#pragma unroll
  for (int k = 0; k < 8; k++) acc8[k] += __shfl_xor(acc8[k], 32);

  // lane writes 4 channels: cbase = cg*8 + half*4 (static-index selects only)
  float a0 = half ? acc8[4] : acc8[0];
  float a1 = half ? acc8[5] : acc8[1];
  float a2 = half ? acc8[6] : acc8[2];
  float a3 = half ? acc8[7] : acc8[3];
  int cbase = cg * 8 + half * 4;
  float4 b = *(const float4*)(bias + cbase);
  float4 o;
  o.x = fmaxf(a0 + b.x, 0.f);
  o.y = fmaxf(a1 + b.y, 0.f);
  o.z = fmaxf(a2 + b.z, 0.f);
  o.w = fmaxf(a3 + b.w, 0.f);
  *(float4*)(out + (size_t)n * 512 + outOffset + cbase) = o;
  if (xout) {
    ushort4 ob;
    ob.x = f2bf(o.x); ob.y = f2bf(o.y); ob.z = f2bf(o.z); ob.w = f2bf(o.w);
    *(ushort4*)(xout + (size_t)n * CH + cbase) = ob;
  }
}

extern "C" void kernel_launch(void* const* d_in, const int* in_sizes, int n_in,
                              void* d_out, int out_size, void* d_ws, size_t ws_size,
                              hipStream_t stream) {
  const float* x   = (const float*)d_in[0];
  const int*   ei  = (const int*)d_in[1];
  const float* W1  = (const float*)d_in[2];
  const float* a1s = (const float*)d_in[3];
  const float* a1d = (const float*)d_in[4];
  const float* b1  = (const float*)d_in[5];
  const float* W2  = (const float*)d_in[6];
  const float* a2s = (const float*)d_in[7];
  const float* a2d = (const float*)d_in[8];
  const float* b2  = (const float*)d_in[9];
  float* out = (float*)d_out;

  char* ws = (char*)d_ws;
  size_t off = 0;
  auto alloc = [&](size_t bytes) -> void* {
    void* p = ws + off;
    off = (off + bytes + 255) & ~(size_t)255;
    return p;
  };
  unsigned short* Hmb    = (unsigned short*)alloc(sizeof(short) * (size_t)NNODES * CH);
  unsigned short* Xb     = (unsigned short*)alloc(sizeof(short) * (size_t)NNODES * CH);
  unsigned short* Wb1    = (unsigned short*)alloc(sizeof(short) * CH * DIN);
  unsigned short* Wb2    = (unsigned short*)alloc(sizeof(short) * CH * CH);
  float*          eS1    = (float*)alloc(sizeof(float) * NNODES);
  float*          eD1    = (float*)alloc(sizeof(float) * NNODES);
  float*          eS2    = (float*)alloc(sizeof(float) * NNODES);
  float*          eD2    = (float*)alloc(sizeof(float) * NNODES);
  int*            rowptr = (int*)alloc(sizeof(int) * (NNODES + 1));
  int*            cursor = (int*)alloc(sizeof(int) * NNODES);
  int*            csrsrc = (int*)alloc(sizeof(int) * ETOT);
  int*            deg    = (int*)alloc(sizeof(int) * NNODES);
  int*            tstate = (int*)alloc(sizeof(int) * NSCAN);

  int nblk4 = (NNODES + 3) / 4;

  // 1) init + weight casts + lookback-state zero (1 dispatch)
  init_and_cast<<<(NNODES + 255) / 256, 256, 0, stream>>>(deg, eS1, eD1, eS2, eD2,
                                                          W1, W2, Wb1, Wb2, tstate);

  // 2) layer-1 GEMM with degree counting fused at the grid tail (overlapped)
  gemm1_deg<<<GEMM_GRID + DEG_BLOCKS, 256, 0, stream>>>(x, Wb1, Hmb, a1s, a1d,
                                                        eS1, eD1, ei, deg);

  // 3) CSR prefix-sum: single-dispatch decoupled lookback (49 blocks)
  scan_lookback<<<NSCAN, 256, 0, stream>>>(deg, rowptr, cursor, tstate);

  // 4) CSR scatter (own dispatch; no spin)
  scatter_kernel<<<(ETOT + 255) / 256, 256, 0, stream>>>(ei, cursor, csrsrc);

  // 5) layer 1 aggregate
  aggregate_kernel<<<nblk4, 256, 0, stream>>>(Hmb, eS1, eD1, rowptr, csrsrc, b1, out, 0, Xb);

  // 6) layer 2 GEMM
  gemm_l2<<<dim3(2, (NNODES + TM - 1) / TM), 256, 0, stream>>>(Xb, Wb2, Hmb, a2s, a2d, eS2, eD2);

  // 7) layer 2 aggregate
  aggregate_kernel<<<nblk4, 256, 0, stream>>>(Hmb, eS2, eD2, rowptr, csrsrc, b2, out, 256,
                                              (unsigned short*)nullptr);
}

// Round 5
// 309.780 us; speedup vs baseline: 1.3233x; 1.0285x over previous
//
#include <hip/hip_runtime.h>
#include <hip/hip_bf16.h>
#include <math.h>

#define NNODES 50000
#define NEDGES 500000
#define ETOT   (NEDGES + NNODES)
#define DIN    128
#define CH     256
#define SLOPE  0.2f

#define SCAN_TILE 1024
#define NSCAN ((NNODES + SCAN_TILE - 1) / SCAN_TILE)   // 49
#define FLAGBIT 0x40000000

typedef __attribute__((ext_vector_type(8))) short short8;
typedef __attribute__((ext_vector_type(4))) float f32x4;
typedef __attribute__((ext_vector_type(2))) float f32x2;

typedef __attribute__((address_space(1))) void gvoid;
typedef __attribute__((address_space(3))) void lvoid;

static __device__ __forceinline__ void gload_lds16(const void* g, void* l) {
  // width-16 global->LDS: lane i lands at ldsbase + i*16 (wave-uniform base)
  __builtin_amdgcn_global_load_lds((const gvoid*)g, (lvoid*)l, 16, 0, 0);
}

static __device__ __forceinline__ float wave_reduce_max(float v) {
#pragma unroll
  for (int off = 32; off > 0; off >>= 1) v = fmaxf(v, __shfl_xor(v, off));
  return v;
}
static __device__ __forceinline__ float wave_reduce_sum(float v) {
#pragma unroll
  for (int off = 32; off > 0; off >>= 1) v += __shfl_xor(v, off);
  return v;
}
static __device__ __forceinline__ int wave_reduce_sum_i(int v) {
#pragma unroll
  for (int off = 32; off > 0; off >>= 1) v += __shfl_xor(v, off);
  return v;
}

static __device__ __forceinline__ unsigned short f2bf(float f) {
  unsigned int u = __float_as_uint(f);
  unsigned int r = (u + 0x7fffu + ((u >> 16) & 1u)) >> 16;
  return (unsigned short)r;
}

// ---------------- fused init + weight cast: one dispatch ----------------
#define W1N4 (CH * DIN / 4)   // 8192
#define W2N4 (CH * CH / 4)    // 16384
__global__ __launch_bounds__(256) void init_and_cast(
    int* __restrict__ deg,
    float* __restrict__ eS1, float* __restrict__ eD1,
    float* __restrict__ eS2, float* __restrict__ eD2,
    const float* __restrict__ W1, const float* __restrict__ W2,
    unsigned short* __restrict__ Wb1, unsigned short* __restrict__ Wb2,
    int* __restrict__ tstate) {
  int i = blockIdx.x * 256 + threadIdx.x;
  if (i < NNODES) {
    deg[i] = 0;
    eS1[i] = 0.f; eD1[i] = 0.f;
    eS2[i] = 0.f; eD2[i] = 0.f;
  }
  if (i < NSCAN) tstate[i] = 0;
  if (i < W1N4 + W2N4) {
    const float* src;
    unsigned short* dst;
    int j;
    if (i < W1N4) { src = W1; dst = Wb1; j = i; }
    else          { src = W2; dst = Wb2; j = i - W1N4; }
    float4 v = *(const float4*)(src + (size_t)j * 4);
    ushort4 o;
    o.x = f2bf(v.x); o.y = f2bf(v.y); o.z = f2bf(v.z); o.w = f2bf(v.w);
    *(ushort4*)(dst + (size_t)j * 4) = o;
  }
}

// ---------------- decoupled-lookback scan: ONE dispatch, 49 blocks only ----------------
__global__ __launch_bounds__(256) void scan_lookback(
    const int* __restrict__ deg, int* __restrict__ rowptr, int* __restrict__ cursor,
    int* __restrict__ tstate) {
  __shared__ int wsums[4];
  __shared__ int s_boff;
  int b = blockIdx.x;
  int tid = threadIdx.x;
  int lane = tid & 63;
  int base = b * SCAN_TILE + tid * 4;
  int d[4];
  int s = 0;
#pragma unroll
  for (int j = 0; j < 4; j++) {
    d[j] = (base + j < NNODES) ? deg[base + j] : 0;
    s += d[j];
  }
  int x = s;
#pragma unroll
  for (int off = 1; off < 64; off <<= 1) {
    int t = __shfl_up(x, off);
    if (lane >= off) x += t;
  }
  if (lane == 63) wsums[tid >> 6] = x;
  __syncthreads();
  int total = wsums[0] + wsums[1] + wsums[2] + wsums[3];
  if (tid == 0)
    __hip_atomic_store(&tstate[b], total | FLAGBIT, __ATOMIC_RELEASE, __HIP_MEMORY_SCOPE_AGENT);
  if (tid < 64) {
    int acc = 0;
    if (lane < b) {
      int v;
      do {
        v = __hip_atomic_load(&tstate[lane], __ATOMIC_ACQUIRE, __HIP_MEMORY_SCOPE_AGENT);
        if (!(v & FLAGBIT)) __builtin_amdgcn_s_sleep(2);
      } while (!(v & FLAGBIT));
      acc = v & ~FLAGBIT;
    }
    acc = wave_reduce_sum_i(acc);
    if (lane == 0) s_boff = acc;
  }
  __syncthreads();
  int boff = s_boff;
  int woff = 0;
  int w = tid >> 6;
  for (int i = 0; i < w; i++) woff += wsums[i];
  int excl = boff + woff + (x - s);
#pragma unroll
  for (int j = 0; j < 4; j++) {
    if (base + j < NNODES) { rowptr[base + j] = excl; cursor[base + j] = excl; }
    excl += d[j];
  }
  if (b == NSCAN - 1 && tid == 0) rowptr[NNODES] = boff + total;
}

__global__ void scatter_kernel(const int* __restrict__ ei, int* __restrict__ cursor,
                               int* __restrict__ csr_src) {
  int e = blockIdx.x * blockDim.x + threadIdx.x;
  if (e >= ETOT) return;
  int src, dst;
  if (e < NEDGES) { src = ei[e]; dst = ei[NEDGES + e]; }
  else            { src = e - NEDGES; dst = src; }
  int slot = atomicAdd(&cursor[dst], 1);
  csr_src[slot] = src;
}

// ---------------- bf16 MFMA GEMM body + fused attention-score epilogue ----------------
// B tile (and A tile when input is bf16) staged via global_load_lds width-16
// into LINEAR LDS with chunk-XOR swizzle applied on BOTH sides (rule #21).
// Layer-1 A (fp32->bf16 conversion) keeps padded VGPR-staged path.
#define TM 128
#define TN 128
#define TK 64
#define LDA (TK + 8)          // padded layout, layer-1 A only
#define LDC (TN + 8)
#define SMEM_SHORTS (TM * LDC)  // 17408 shorts = 34816 B (covers all layouts)
#define GEMM_GRID (2 * ((NNODES + TM - 1) / TM))      // 782
#define DEG_BLOCKS ((ETOT + 255) / 256)               // 2149

template <bool XF>
static __device__ __forceinline__ void gemm_body(
    const float* __restrict__ Xf, const unsigned short* __restrict__ Xb,
    const unsigned short* __restrict__ W, int K,
    unsigned short* __restrict__ Hout, int M,
    const float* __restrict__ a_src, const float* __restrict__ a_dst,
    float* __restrict__ eS, float* __restrict__ eD,
    int bm, int bn) {
  __shared__ short smem[SMEM_SHORTS];
  short* As = smem;                                   // padded 9216 or linear 8192
  short* Bs = smem + (XF ? TM * LDA : TM * TK);       // linear 8192
  short* Cs = smem;
  int tid = threadIdx.x;
  int wid = tid >> 6;
  int lane = tid & 63;
  int wm = (wid & 1) * 64;
  int wn = (wid >> 1) * 64;
  int lrow = lane & 15;
  int lk8 = (lane >> 4) * 8;

  int srow = tid >> 3;          // layer-1 A staging row
  int skoff = (tid & 7) * 8;

  int rsub = lane >> 3;         // glds source mapping: lane -> (row R+rsub, chunk)
  int csub = lane & 7;
  int schunk = (csub ^ rsub) << 3;   // inverse-swizzled source chunk (shorts)

  f32x4 acc[4][4] = {};

  for (int k0 = 0; k0 < K; k0 += TK) {
    // ---- B tile: 4 glds instrs/wave, 8 rows each (linear dest + pre-swizzled src)
#pragma unroll
    for (int i = 0; i < 4; i++) {
      int R = i * 32 + wid * 8;
      const unsigned short* g = W + (size_t)(bn + R + rsub) * K + k0 + schunk;
      gload_lds16(g, &Bs[R * TK]);
    }
    if (XF) {
      // ---- A tile: fp32 load + convert + padded ds_write ----
#pragma unroll
      for (int i = 0; i < 4; i++) {
        int r = srow + 32 * i;
        int gm = bm + r;
        short8 v = {};
        if (gm < M) {
          const float* p = Xf + (size_t)gm * DIN + k0 + skoff;
          float4 f0 = *(const float4*)(p);
          float4 f1 = *(const float4*)(p + 4);
          v[0] = (short)f2bf(f0.x); v[1] = (short)f2bf(f0.y);
          v[2] = (short)f2bf(f0.z); v[3] = (short)f2bf(f0.w);
          v[4] = (short)f2bf(f1.x); v[5] = (short)f2bf(f1.y);
          v[6] = (short)f2bf(f1.z); v[7] = (short)f2bf(f1.w);
        }
        *(short8*)(&As[r * LDA + skoff]) = v;
      }
    } else {
      // ---- A tile: bf16 direct glds (rows >= M read in-workspace garbage; masked downstream)
#pragma unroll
      for (int i = 0; i < 4; i++) {
        int R = i * 32 + wid * 8;
        const unsigned short* g = Xb + (size_t)(bm + R + rsub) * K + k0 + schunk;
        gload_lds16(g, &As[R * TK]);
      }
    }
    __syncthreads();
#pragma unroll
    for (int kk = 0; kk < TK; kk += 32) {
      short8 a[4], b[4];
#pragma unroll
      for (int mi = 0; mi < 4; mi++) {
        int ar = wm + mi * 16 + lrow;
        if (XF) {
          a[mi] = *(const short8*)(&As[ar * LDA + kk + lk8]);
        } else {
          int ac = (kk + lk8) >> 3;
          a[mi] = *(const short8*)(&As[ar * TK + ((ac ^ (ar & 7)) << 3)]);
        }
      }
#pragma unroll
      for (int ni = 0; ni < 4; ni++) {
        int br = wn + ni * 16 + lrow;
        int bc = (kk + lk8) >> 3;
        b[ni] = *(const short8*)(&Bs[br * TK + ((bc ^ (br & 7)) << 3)]);
      }
#pragma unroll
      for (int mi = 0; mi < 4; mi++)
#pragma unroll
        for (int ni = 0; ni < 4; ni++)
          acc[mi][ni] = __builtin_amdgcn_mfma_f32_16x16x32_bf16(a[mi], b[ni], acc[mi][ni], 0, 0, 0);
    }
    __syncthreads();
  }

  int crow = (lane >> 4) * 4;
  int ccol = lane & 15;

  // ---- fused score epilogue ----
  float asv[4], adv[4];
#pragma unroll
  for (int ni = 0; ni < 4; ni++) {
    int c = bn + wn + ni * 16 + ccol;
    asv[ni] = a_src[c];
    adv[ni] = a_dst[c];
  }
#pragma unroll
  for (int mi = 0; mi < 4; mi++) {
#pragma unroll
    for (int r = 0; r < 4; r++) {
      float s = 0.f, d = 0.f;
#pragma unroll
      for (int ni = 0; ni < 4; ni++) {
        float h = acc[mi][ni][r];
        s += h * asv[ni];
        d += h * adv[ni];
      }
#pragma unroll
      for (int off = 1; off < 16; off <<= 1) {
        s += __shfl_xor(s, off);
        d += __shfl_xor(d, off);
      }
      int gm = bm + wm + mi * 16 + crow + r;
      if (ccol == 0 && gm < M) {
        atomicAdd(&eS[gm], s);
        atomicAdd(&eD[gm], d);
      }
    }
  }

  // ---- C-store via padded LDS tile -> coalesced short8 global stores ----
#pragma unroll
  for (int mi = 0; mi < 4; mi++) {
#pragma unroll
    for (int ni = 0; ni < 4; ni++) {
#pragma unroll
      for (int r = 0; r < 4; r++) {
        int row = wm + mi * 16 + crow + r;
        int col = wn + ni * 16 + ccol;
        Cs[row * LDC + col] = (short)f2bf(acc[mi][ni][r]);
      }
    }
  }
  __syncthreads();
  int orow = tid >> 4;
  int ocol = (tid & 15) * 8;
#pragma unroll
  for (int pp = 0; pp < 8; pp++) {
    int row = pp * 16 + orow;
    int gm = bm + row;
    if (gm < M) {
      short8 v = *(const short8*)(&Cs[row * LDC + ocol]);
      *(short8*)(&Hout[(size_t)gm * CH + bn + ocol]) = v;
    }
  }
}

// layer-1 GEMM with degree-count blocks fused at the grid tail (no polling)
__global__ __launch_bounds__(256) void gemm1_deg(
    const float* __restrict__ Xf, const unsigned short* __restrict__ W,
    unsigned short* __restrict__ Hout,
    const float* __restrict__ a_src, const float* __restrict__ a_dst,
    float* __restrict__ eS, float* __restrict__ eD,
    const int* __restrict__ ei, int* __restrict__ deg) {
  if (blockIdx.x >= GEMM_GRID) {
    int e = (blockIdx.x - GEMM_GRID) * 256 + threadIdx.x;
    if (e < ETOT) {
      int dst = (e < NEDGES) ? ei[NEDGES + e] : (e - NEDGES);
      atomicAdd(&deg[dst], 1);
    }
    return;
  }
  int bn = (blockIdx.x & 1) * TN;
  int bm = (blockIdx.x >> 1) * TM;
  gemm_body<true>(Xf, (const unsigned short*)nullptr, W, DIN, Hout, NNODES,
                  a_src, a_dst, eS, eD, bm, bn);
}

__global__ __launch_bounds__(256) void gemm_l2(
    const unsigned short* __restrict__ Xb, const unsigned short* __restrict__ W,
    unsigned short* __restrict__ Hout,
    const float* __restrict__ a_src, const float* __restrict__ a_dst,
    float* __restrict__ eS, float* __restrict__ eD) {
  int bn = blockIdx.x * TN;
  int bm = blockIdx.y * TM;
  gemm_body<false>((const float*)nullptr, Xb, W, CH, Hout, NNODES,
                   a_src, a_dst, eS, eD, bm, bn);
}

// ---------------- per-node softmax + aggregate (+bias, +ReLU) ----------------
// Wave per node. Weighted pass: half-wave per edge of a pair, 16 B/lane loads;
// float2 accumulators -> v_pk_fma_f32 (halves FMA instrs); wave-uniform early
// exits skip entirely-invalid tail slots (deg~11 vs batch 16).
__global__ __launch_bounds__(256) void aggregate_kernel(
    const unsigned short* __restrict__ Hmb, const float* __restrict__ eS,
    const float* __restrict__ eD, const int* __restrict__ rowptr,
    const int* __restrict__ csr_src, const float* __restrict__ bias,
    float* __restrict__ out, int outOffset, unsigned short* __restrict__ xout) {
  int n = blockIdx.x * 4 + (threadIdx.x >> 6);
  if (n >= NNODES) return;
  int lane = threadIdx.x & 63;
  int half = lane >> 5;        // which edge of the pair this lane serves
  int cg = lane & 31;          // channel group: channels cg*8 .. cg*8+7
  int beg = rowptr[n], end = rowptr[n + 1];
  int degs = __builtin_amdgcn_readfirstlane(end - beg);  // wave-uniform scalar
  float ed = eD[n];

  f32x2 acc2[4] = {};          // 8 channels as 4 packed pairs

  if (degs <= 64) {
    int src = 0;
    float e = -1e30f;
    if (lane < degs) {
      src = csr_src[beg + lane];              // coalesced
      float t = eS[src] + ed;                 // lane-parallel gather
      e = (t >= 0.f) ? t : SLOPE * t;
    }
    float m = wave_reduce_max(e);
    float p = (lane < degs) ? __expf(e - m) : 0.f;
    float inv = 1.f / (wave_reduce_sum(p) + 1e-16f);
    float av = p * inv;                       // this lane's alpha

    for (int j0 = 0; j0 < degs; j0 += 16) {
      uint4 hv[8];
      f32x2 al2[8];
#pragma unroll
      for (int t = 0; t < 8; t++) {
        if (j0 + 2 * t < degs) {              // uniform guard: skip dead tail slots
          int j = j0 + 2 * t + half;
          int jj = (j < degs) ? j : degs - 1; // partial pair dups last edge (L1-hot)
          int sj = __shfl(src, jj);
          float aj = __shfl(av, jj);
          float a = (j < degs) ? aj : 0.f;
          al2[t] = (f32x2){a, a};
          hv[t] = *(const uint4*)(Hmb + (size_t)sj * CH + cg * 8);
        }
      }
#pragma unroll
      for (int t = 0; t < 8; t++) {
        if (j0 + 2 * t < degs) {
          acc2[0] += al2[t] * (f32x2){__uint_as_float(hv[t].x << 16),
                                      __uint_as_float(hv[t].x & 0xffff0000u)};
          acc2[1] += al2[t] * (f32x2){__uint_as_float(hv[t].y << 16),
                                      __uint_as_float(hv[t].y & 0xffff0000u)};
          acc2[2] += al2[t] * (f32x2){__uint_as_float(hv[t].z << 16),
                                      __uint_as_float(hv[t].z & 0xffff0000u)};
          acc2[3] += al2[t] * (f32x2){__uint_as_float(hv[t].w << 16),
                                      __uint_as_float(hv[t].w & 0xffff0000u)};
        }
      }
    }
  } else {
    float m = -1e30f;
    for (int i = lane; i < degs; i += 64) {
      float e = eS[csr_src[beg + i]] + ed;
      e = (e >= 0.f) ? e : SLOPE * e;
      m = fmaxf(m, e);
    }
    m = wave_reduce_max(m);
    float ds = 0.f;
    for (int i = lane; i < degs; i += 64) {
      float e = eS[csr_src[beg + i]] + ed;
      e = (e >= 0.f) ? e : SLOPE * e;
      ds += __expf(e - m);
    }
    float inv = 1.f / (wave_reduce_sum(ds) + 1e-16f);
    for (int j = 0; j < degs; j += 2) {
      int jj = j + half;
      int k = beg + ((jj < degs) ? jj : degs - 1);
      int s = csr_src[k];
      float e = eS[s] + ed;
      e = (e >= 0.f) ? e : SLOPE * e;
      float alpha = (jj < degs) ? __expf(e - m) * inv : 0.f;
      f32x2 a2 = {alpha, alpha};
      uint4 u = *(const uint4*)(Hmb + (size_t)s * CH + cg * 8);
      acc2[0] += a2 * (f32x2){__uint_as_float(u.x << 16), __uint_as_float(u.x & 0xffff0000u)};
      acc2[1] += a2 * (f32x2){__uint_as_float(u.y << 16), __uint_as_float(u.y & 0xffff0000u)};
      acc2[2] += a2 * (f32x2){__uint_as_float(u.z << 16), __uint_as_float(u.z & 0xffff0000u)};
      acc2[3] += a2 * (f32x2){__uint_as_float(u.w << 16), __uint_as_float(u.w & 0xffff0000u)};
    }
  }

  // combine the two half-wave partial sums (even-j half + odd-j half)
#pragma unroll
  for (int k = 0; k < 4; k++) {
    acc2[k].x += __shfl_xor(acc2[k].x, 32);
    acc2[k].y += __shfl_xor(acc2[k].y, 32);
  }

  // lane writes 4 channels: cbase = cg*8 + half*4 (static-index selects only)
  f32x2 p0 = half ? acc2[2] : acc2[0];
  f32x2 p1 = half ? acc2[3] : acc2[1];
  int cbase = cg * 8 + half * 4;
  float4 b = *(const float4*)(bias + cbase);
  float4 o;
  o.x = fmaxf(p0.x + b.x, 0.f);
  o.y = fmaxf(p0.y + b.y, 0.f);
  o.z = fmaxf(p1.x + b.z, 0.f);
  o.w = fmaxf(p1.y + b.w, 0.f);
  *(float4*)(out + (size_t)n * 512 + outOffset + cbase) = o;
  if (xout) {
    ushort4 ob;
    ob.x = f2bf(o.x); ob.y = f2bf(o.y); ob.z = f2bf(o.z); ob.w = f2bf(o.w);
    *(ushort4*)(xout + (size_t)n * CH + cbase) = ob;
  }
}

extern "C" void kernel_launch(void* const* d_in, const int* in_sizes, int n_in,
                              void* d_out, int out_size, void* d_ws, size_t ws_size,
                              hipStream_t stream) {
  const float* x   = (const float*)d_in[0];
  const int*   ei  = (const int*)d_in[1];
  const float* W1  = (const float*)d_in[2];
  const float* a1s = (const float*)d_in[3];
  const float* a1d = (const float*)d_in[4];
  const float* b1  = (const float*)d_in[5];
  const float* W2  = (const float*)d_in[6];
  const float* a2s = (const float*)d_in[7];
  const float* a2d = (const float*)d_in[8];
  const float* b2  = (const float*)d_in[9];
  float* out = (float*)d_out;

  char* ws = (char*)d_ws;
  size_t off = 0;
  auto alloc = [&](size_t bytes) -> void* {
    void* p = ws + off;
    off = (off + bytes + 255) & ~(size_t)255;
    return p;
  };
  unsigned short* Hmb    = (unsigned short*)alloc(sizeof(short) * (size_t)NNODES * CH);
  unsigned short* Xb     = (unsigned short*)alloc(sizeof(short) * (size_t)NNODES * CH);
  unsigned short* Wb1    = (unsigned short*)alloc(sizeof(short) * CH * DIN);
  unsigned short* Wb2    = (unsigned short*)alloc(sizeof(short) * CH * CH);
  float*          eS1    = (float*)alloc(sizeof(float) * NNODES);
  float*          eD1    = (float*)alloc(sizeof(float) * NNODES);
  float*          eS2    = (float*)alloc(sizeof(float) * NNODES);
  float*          eD2    = (float*)alloc(sizeof(float) * NNODES);
  int*            rowptr = (int*)alloc(sizeof(int) * (NNODES + 1));
  int*            cursor = (int*)alloc(sizeof(int) * NNODES);
  int*            csrsrc = (int*)alloc(sizeof(int) * ETOT);
  int*            deg    = (int*)alloc(sizeof(int) * NNODES);
  int*            tstate = (int*)alloc(sizeof(int) * NSCAN);

  int nblk4 = (NNODES + 3) / 4;

  // 1) init + weight casts + lookback-state zero (1 dispatch)
  init_and_cast<<<(NNODES + 255) / 256, 256, 0, stream>>>(deg, eS1, eD1, eS2, eD2,
                                                          W1, W2, Wb1, Wb2, tstate);

  // 2) layer-1 GEMM with degree counting fused at the grid tail (no polling)
  gemm1_deg<<<GEMM_GRID + DEG_BLOCKS, 256, 0, stream>>>(x, Wb1, Hmb, a1s, a1d,
                                                        eS1, eD1, ei, deg);

  // 3) CSR prefix-sum: single-dispatch decoupled lookback (49 blocks)
  scan_lookback<<<NSCAN, 256, 0, stream>>>(deg, rowptr, cursor, tstate);

  // 4) CSR scatter
  scatter_kernel<<<(ETOT + 255) / 256, 256, 0, stream>>>(ei, cursor, csrsrc);

  // 5) layer 1 aggregate
  aggregate_kernel<<<nblk4, 256, 0, stream>>>(Hmb, eS1, eD1, rowptr, csrsrc, b1, out, 0, Xb);

  // 6) layer 2 GEMM
  gemm_l2<<<dim3(2, (NNODES + TM - 1) / TM), 256, 0, stream>>>(Xb, Wb2, Hmb, a2s, a2d, eS2, eD2);

  // 7) layer 2 aggregate
  aggregate_kernel<<<nblk4, 256, 0, stream>>>(Hmb, eS2, eD2, rowptr, csrsrc, b2, out, 256,
                                              (unsigned short*)nullptr);
}